// Round 3
// baseline (276.379 us; speedup 1.0000x reference)
//
#include <hip/hip_runtime.h>
#include <math.h>

typedef __attribute__((ext_vector_type(8))) short bf16x8;
typedef __attribute__((ext_vector_type(4))) float f32x4;
typedef unsigned short ushort_t;

static __device__ __forceinline__ unsigned short f2b(float x) {
  unsigned int u = __float_as_uint(x);
  u += 0x7FFFu + ((u >> 16) & 1u);  // round-to-nearest-even
  return (unsigned short)(u >> 16);
}

// ---------------- prep kernel (UNCHANGED from R2 on purpose) ----------------
static __device__ __forceinline__ void transpose_tile(
    const float* __restrict__ src, ushort_t* __restrict__ dst, int srcC,
    int dstC, int r0, int c0, ushort_t (*T)[72], int t) {
#pragma unroll
  for (int j = 0; j < 4; ++j) {
    int idx = j * 256 + t;
    int lr = idx >> 4;
    int lc = (idx & 15) << 2;
    float4 v = *(const float4*)(&src[(size_t)(r0 + lr) * srcC + c0 + lc]);
    T[lr][lc + 0] = f2b(v.x);
    T[lr][lc + 1] = f2b(v.y);
    T[lr][lc + 2] = f2b(v.z);
    T[lr][lc + 3] = f2b(v.w);
  }
  __syncthreads();
#pragma unroll
  for (int j = 0; j < 2; ++j) {
    int oidx = j * 256 + t;
    int lc = oidx >> 3;
    int rch = (oidx & 7) << 3;
    ushort_t tmp[8];
#pragma unroll
    for (int k = 0; k < 8; ++k) tmp[k] = T[rch + k][lc];
    *(uint4*)(&dst[(size_t)(c0 + lc) * dstC + r0 + rch]) = *(uint4*)tmp;
  }
}

__global__ void prep(const float* __restrict__ W1, const float* __restrict__ W2,
                     const float* __restrict__ mem, ushort_t* __restrict__ W1T,
                     ushort_t* __restrict__ W2T, ushort_t* __restrict__ memB,
                     float* __restrict__ msq) {
  __shared__ ushort_t T[64][72];
  int b = blockIdx.x;
  int t = threadIdx.x;
  if (b < 32) {
    int tr = b >> 3, tc = b & 7;
    transpose_tile(W1, W1T, 512, 256, tr * 64, tc * 64, T, t);
  } else if (b < 64) {
    int bb = b - 32;
    int tr = bb >> 2, tc = bb & 3;
    transpose_tile(W2, W2T, 256, 512, tr * 64, tc * 64, T, t);
  } else {
    for (int i = t; i < 16384; i += 256) {
      int r = i >> 8;
      memB[i] = (r < 50) ? f2b(mem[i]) : (ushort_t)0;
    }
    int r = t >> 2, seg = t & 3;
    float s = 0.f;
    if (r < 50) {
#pragma unroll
      for (int i = 0; i < 16; i += 4) {
        float4 v = *(const float4*)(&mem[r * 256 + seg * 64 + i * 4]);
        s += v.x * v.x + v.y * v.y + v.z * v.z + v.w * v.w;
      }
    }
    s += __shfl_xor(s, 1, 64);
    s += __shfl_xor(s, 2, 64);
    if (seg == 0) msq[r] = (r < 50) ? s : 1e30f;
  }
}

// ---------------- fused main kernel: 32 tokens/block, LDS 25600 B ----------------
// LDS map (all XOR-swizzled in 16B chunks: slot = chunk ^ (row & 7), no pads):
//   [0,     16384)  Xs   [32 tok][256] bf16   (X data; later: normalized feats)
//   [16384, 24576)  Hs   [32 tok][128] bf16   (Phase 1 only)
//   [16384, 24704)  distS[32][65] fp32        (Phase 3-4; Hs dead)
//   [16384, 17408)  psum/psumsq [4][32] fp32  (Phase 2a only; before distS)
//   [24704, 25600)  fsqp[4][32] + muS/rstdS/fsqS [32]
__global__ __launch_bounds__(256, 5) void fused_main(
    const float* __restrict__ X, const float* __restrict__ b1v,
    const float* __restrict__ b2v, const float* __restrict__ gammav,
    const float* __restrict__ betav, const ushort_t* __restrict__ W1T,
    const ushort_t* __restrict__ W2T, const ushort_t* __restrict__ memB,
    const float* __restrict__ msq, float* __restrict__ out) {
  __shared__ __align__(16) char smem[25600];
  char* Xs = smem;                    // byte-addressed, swizzled
  char* Hs = smem + 16384;
  float* distS  = (float*)(smem + 16384);
  float* psum   = (float*)(smem + 16384);  // overlay: dead before distS written
  float* psumsq = (float*)(smem + 16896);
  float* fsqp   = (float*)(smem + 24704);  // [4][32]
  float* muS    = (float*)(smem + 25216);
  float* rstdS  = (float*)(smem + 25344);
  float* fsqS   = (float*)(smem + 25472);

  const int tid = threadIdx.x;
  const int wid = tid >> 6;
  const int lane = tid & 63;
  const int l16 = lane & 15;
  const int quad = lane >> 4;

  // ---- Phase 0: stage X tile [32][256] fp32 -> LDS bf16 (swizzled) ----
  const float4* X4 = (const float4*)(X + (size_t)blockIdx.x * 32 * 256);
#pragma unroll
  for (int j = 0; j < 8; ++j) {
    int idx = j * 256 + tid;            // 2048 float4 = [32 rows][64 f4]
    float4 v = X4[idx];
    int row = idx >> 6;
    int c = (idx & 63) >> 1;            // 16B chunk index (0..31)
    int half = idx & 1;
    int slot = c ^ (row & 7);
    unsigned int p0 = f2b(v.x) | ((unsigned int)f2b(v.y) << 16);
    unsigned int p1 = f2b(v.z) | ((unsigned int)f2b(v.w) << 16);
    *(uint2*)(Xs + row * 512 + slot * 16 + half * 8) = make_uint2(p0, p1);
  }

  // F^T accumulators: (fcol = wid*64 + mt*16 + quad*4 + reg, token = nt*16 + l16)
  f32x4 acc2[4][2];
#pragma unroll
  for (int mt = 0; mt < 4; ++mt) {
    const float4 bb = *(const float4*)(&b2v[wid * 64 + mt * 16 + quad * 4]);
#pragma unroll
    for (int nt = 0; nt < 2; ++nt) {
      acc2[mt][nt][0] = bb.x; acc2[mt][nt][1] = bb.y;
      acc2[mt][nt][2] = bb.z; acc2[mt][nt][3] = bb.w;
    }
  }

  __syncthreads();

  // ---- Phase 1: chunked GEMM1 -> relu -> Hs; GEMM2 accumulate ----
  for (int cc = 0; cc < 4; ++cc) {
    int hbase = cc * 128 + wid * 32;
    f32x4 acc1[2][2];
#pragma unroll
    for (int mt = 0; mt < 2; ++mt) {
      const float4 bb = *(const float4*)(&b1v[hbase + mt * 16 + quad * 4]);
#pragma unroll
      for (int nt = 0; nt < 2; ++nt) {
        acc1[mt][nt][0] = bb.x; acc1[mt][nt][1] = bb.y;
        acc1[mt][nt][2] = bb.z; acc1[mt][nt][3] = bb.w;
      }
    }
#pragma unroll
    for (int kk = 0; kk < 8; ++kk) {
      int k0 = kk * 32 + quad * 8;
      bf16x8 a[2], b[2];
#pragma unroll
      for (int mt = 0; mt < 2; ++mt)
        a[mt] = *(const bf16x8*)(W1T + (hbase + mt * 16 + l16) * 256 + k0);
      int c = kk * 4 + quad;
#pragma unroll
      for (int nt = 0; nt < 2; ++nt) {
        int t = nt * 16 + l16;
        b[nt] = *(const bf16x8*)(Xs + t * 512 + (c ^ (t & 7)) * 16);
      }
#pragma unroll
      for (int mt = 0; mt < 2; ++mt)
#pragma unroll
        for (int nt = 0; nt < 2; ++nt)
          acc1[mt][nt] = __builtin_amdgcn_mfma_f32_16x16x32_bf16(
              a[mt], b[nt], acc1[mt][nt], 0, 0, 0);
    }
    __syncthreads();  // previous GEMM2 done reading Hs
#pragma unroll
    for (int mt = 0; mt < 2; ++mt) {
#pragma unroll
      for (int nt = 0; nt < 2; ++nt) {
        int token = nt * 16 + l16;
        int hloc = wid * 32 + mt * 16 + quad * 4;
        int c = wid * 4 + mt * 2 + (quad >> 1);
        int half = quad & 1;
        int slot = c ^ (token & 7);
        f32x4 v = acc1[mt][nt];
        unsigned int p0 = f2b(fmaxf(v[0], 0.f)) | ((unsigned int)f2b(fmaxf(v[1], 0.f)) << 16);
        unsigned int p1 = f2b(fmaxf(v[2], 0.f)) | ((unsigned int)f2b(fmaxf(v[3], 0.f)) << 16);
        *(uint2*)(Hs + token * 256 + slot * 16 + half * 8) = make_uint2(p0, p1);
        (void)hloc;
      }
    }
    __syncthreads();
#pragma unroll
    for (int k2 = 0; k2 < 4; ++k2) {
      int c = k2 * 4 + quad;
      bf16x8 a[4], b[2];
#pragma unroll
      for (int mt = 0; mt < 4; ++mt)
        a[mt] = *(const bf16x8*)(W2T + (wid * 64 + mt * 16 + l16) * 512 +
                                 cc * 128 + k2 * 32 + quad * 8);
#pragma unroll
      for (int nt = 0; nt < 2; ++nt) {
        int t = nt * 16 + l16;
        b[nt] = *(const bf16x8*)(Hs + t * 256 + (c ^ (t & 7)) * 16);
      }
#pragma unroll
      for (int mt = 0; mt < 4; ++mt)
#pragma unroll
        for (int nt = 0; nt < 2; ++nt)
          acc2[mt][nt] = __builtin_amdgcn_mfma_f32_16x16x32_bf16(
              a[mt], b[nt], acc2[mt][nt], 0, 0, 0);
    }
  }
  __syncthreads();  // Hs dead; psum overlay becomes safe

  // ---- Phase 2a: per-token sum/sumsq for LayerNorm ----
#pragma unroll
  for (int nt = 0; nt < 2; ++nt) {
    float s = 0.f, sq = 0.f;
#pragma unroll
    for (int mt = 0; mt < 4; ++mt)
#pragma unroll
      for (int r = 0; r < 4; ++r) {
        float v = acc2[mt][nt][r];
        s += v; sq += v * v;
      }
    s += __shfl_xor(s, 16, 64); sq += __shfl_xor(sq, 16, 64);
    s += __shfl_xor(s, 32, 64); sq += __shfl_xor(sq, 32, 64);
    if (quad == 0) {
      psum[wid * 32 + nt * 16 + l16] = s;
      psumsq[wid * 32 + nt * 16 + l16] = sq;
    }
  }
  __syncthreads();
  if (tid < 32) {
    float s = psum[tid] + psum[32 + tid] + psum[64 + tid] + psum[96 + tid];
    float sq = psumsq[tid] + psumsq[32 + tid] + psumsq[64 + tid] + psumsq[96 + tid];
    float mu = s * (1.f / 256.f);
    float var = sq * (1.f / 256.f) - mu * mu;
    muS[tid] = mu;
    rstdS[tid] = rsqrtf(var + 1e-5f);
  }
  __syncthreads();

  // ---- Phase 2b: normalize, write feats bf16 (token-major, swizzled), fsq ----
  {
    float4 g[4], be[4];
#pragma unroll
    for (int mt = 0; mt < 4; ++mt) {
      g[mt]  = *(const float4*)(&gammav[wid * 64 + mt * 16 + quad * 4]);
      be[mt] = *(const float4*)(&betav[wid * 64 + mt * 16 + quad * 4]);
    }
#pragma unroll
    for (int nt = 0; nt < 2; ++nt) {
      int token = nt * 16 + l16;
      float mu = muS[token], rs = rstdS[token];
      float fs = 0.f;
#pragma unroll
      for (int mt = 0; mt < 4; ++mt) {
        float y0 = (acc2[mt][nt][0] - mu) * rs * g[mt].x + be[mt].x;
        float y1 = (acc2[mt][nt][1] - mu) * rs * g[mt].y + be[mt].y;
        float y2 = (acc2[mt][nt][2] - mu) * rs * g[mt].z + be[mt].z;
        float y3 = (acc2[mt][nt][3] - mu) * rs * g[mt].w + be[mt].w;
        fs += y0 * y0 + y1 * y1 + y2 * y2 + y3 * y3;
        int c = wid * 8 + mt * 2 + (quad >> 1);
        int half = quad & 1;
        int slot = c ^ (token & 7);
        unsigned int p0 = f2b(y0) | ((unsigned int)f2b(y1) << 16);
        unsigned int p1 = f2b(y2) | ((unsigned int)f2b(y3) << 16);
        *(uint2*)(Xs + token * 512 + slot * 16 + half * 8) = make_uint2(p0, p1);
      }
      fs += __shfl_xor(fs, 16, 64);
      fs += __shfl_xor(fs, 32, 64);
      if (quad == 0) fsqp[wid * 32 + token] = fs;
    }
  }
  __syncthreads();

  if (tid < 32)
    fsqS[tid] = fsqp[tid] + fsqp[32 + tid] + fsqp[64 + tid] + fsqp[96 + tid];

  // ---- Phase 3: dots GEMM. wave quadrant: token-half = wid&1, memcol-half = wid>>1
  const int th = wid & 1;
  const int mh = wid >> 1;
  f32x4 acc3[2];
#pragma unroll
  for (int nt = 0; nt < 2; ++nt) {
    acc3[nt][0] = 0.f; acc3[nt][1] = 0.f; acc3[nt][2] = 0.f; acc3[nt][3] = 0.f;
  }
#pragma unroll
  for (int kk = 0; kk < 8; ++kk) {
    int c = kk * 4 + quad;
    int t = th * 16 + l16;
    bf16x8 a = *(const bf16x8*)(Xs + t * 512 + (c ^ (t & 7)) * 16);
#pragma unroll
    for (int nt = 0; nt < 2; ++nt) {
      int mrow = mh * 32 + nt * 16 + l16;
      bf16x8 b = *(const bf16x8*)(memB + mrow * 256 + kk * 32 + quad * 8);
      acc3[nt] = __builtin_amdgcn_mfma_f32_16x16x32_bf16(a, b, acc3[nt], 0, 0, 0);
    }
  }
  __syncthreads();  // fsqS visible; all waves done reading Xs; distS overlay safe
  {
    float4 fsq4 = *(const float4*)(&fsqS[th * 16 + quad * 4]);
#pragma unroll
    for (int nt = 0; nt < 2; ++nt) {
      int col = mh * 32 + nt * 16 + l16;
      float mq = msq[col];
#pragma unroll
      for (int r = 0; r < 4; ++r) {
        float fv = (r == 0) ? fsq4.x : (r == 1) ? fsq4.y : (r == 2) ? fsq4.z : fsq4.w;
        float d2 = fv + mq - 2.f * acc3[nt][r];
        float d = sqrtf(fmaxf(d2, 0.f));
        int row = th * 16 + quad * 4 + r;
        distS[row * 65 + col] = d;
      }
    }
  }
  __syncthreads();

  // ---- Phase 4: top-5 smallest of 50, mean, sigmoid ----
  if (tid < 32) {
    float b0 = 1e30f, b1 = 1e30f, b2 = 1e30f, b3 = 1e30f, b4 = 1e30f;
    const float* dr = &distS[tid * 65];
    for (int j = 0; j < 50; ++j) {
      float v = dr[j];
      b4 = fminf(b4, v);
      float t;
      if (b4 < b3) { t = b3; b3 = b4; b4 = t; }
      if (b3 < b2) { t = b2; b2 = b3; b3 = t; }
      if (b2 < b1) { t = b1; b1 = b2; b2 = t; }
      if (b1 < b0) { t = b0; b0 = b1; b1 = t; }
    }
    float avg = (b0 + b1 + b2 + b3 + b4) * 0.2f;
    out[blockIdx.x * 32 + tid] = 1.f / (1.f + __expf(-(avg - 1.f)));
  }
}

// ---------------- launch ----------------
extern "C" void kernel_launch(void* const* d_in, const int* in_sizes, int n_in,
                              void* d_out, int out_size, void* d_ws, size_t ws_size,
                              hipStream_t stream) {
  const float* X   = (const float*)d_in[0];
  const float* mem = (const float*)d_in[1];
  const float* W1  = (const float*)d_in[2];
  const float* b1  = (const float*)d_in[3];
  const float* W2  = (const float*)d_in[4];
  const float* b2  = (const float*)d_in[5];
  const float* g   = (const float*)d_in[6];
  const float* be  = (const float*)d_in[7];
  float* out = (float*)d_out;

  ushort_t* W1T  = (ushort_t*)d_ws;
  ushort_t* W2T  = W1T + 131072;
  ushort_t* memB = W2T + 131072;
  float* msq = (float*)(memB + 16384);

  prep<<<65, 256, 0, stream>>>(W1, W2, mem, W1T, W2T, memB, msq);
  fused_main<<<2048, 256, 0, stream>>>(X, b1, b2, g, be, W1T, W2T, memB, msq, out);
}

// Round 4
// 248.960 us; speedup vs baseline: 1.1101x; 1.1101x over previous
//
#include <hip/hip_runtime.h>
#include <math.h>

typedef __attribute__((ext_vector_type(8))) short bf16x8;
typedef __attribute__((ext_vector_type(4))) float f32x4;
typedef unsigned short ushort_t;

static __device__ __forceinline__ unsigned short f2b(float x) {
  unsigned int u = __float_as_uint(x);
  u += 0x7FFFu + ((u >> 16) & 1u);  // round-to-nearest-even
  return (unsigned short)(u >> 16);
}

// ---------------- prep kernel (unchanged) ----------------
static __device__ __forceinline__ void transpose_tile(
    const float* __restrict__ src, ushort_t* __restrict__ dst, int srcC,
    int dstC, int r0, int c0, ushort_t (*T)[72], int t) {
#pragma unroll
  for (int j = 0; j < 4; ++j) {
    int idx = j * 256 + t;
    int lr = idx >> 4;
    int lc = (idx & 15) << 2;
    float4 v = *(const float4*)(&src[(size_t)(r0 + lr) * srcC + c0 + lc]);
    T[lr][lc + 0] = f2b(v.x);
    T[lr][lc + 1] = f2b(v.y);
    T[lr][lc + 2] = f2b(v.z);
    T[lr][lc + 3] = f2b(v.w);
  }
  __syncthreads();
#pragma unroll
  for (int j = 0; j < 2; ++j) {
    int oidx = j * 256 + t;
    int lc = oidx >> 3;
    int rch = (oidx & 7) << 3;
    ushort_t tmp[8];
#pragma unroll
    for (int k = 0; k < 8; ++k) tmp[k] = T[rch + k][lc];
    *(uint4*)(&dst[(size_t)(c0 + lc) * dstC + r0 + rch]) = *(uint4*)tmp;
  }
}

__global__ void prep(const float* __restrict__ W1, const float* __restrict__ W2,
                     const float* __restrict__ mem, ushort_t* __restrict__ W1T,
                     ushort_t* __restrict__ W2T, ushort_t* __restrict__ memB,
                     float* __restrict__ msq) {
  __shared__ ushort_t T[64][72];
  int b = blockIdx.x;
  int t = threadIdx.x;
  if (b < 32) {
    int tr = b >> 3, tc = b & 7;
    transpose_tile(W1, W1T, 512, 256, tr * 64, tc * 64, T, t);
  } else if (b < 64) {
    int bb = b - 32;
    int tr = bb >> 2, tc = bb & 3;
    transpose_tile(W2, W2T, 256, 512, tr * 64, tc * 64, T, t);
  } else {
    for (int i = t; i < 16384; i += 256) {
      int r = i >> 8;
      memB[i] = (r < 50) ? f2b(mem[i]) : (ushort_t)0;
    }
    int r = t >> 2, seg = t & 3;
    float s = 0.f;
    if (r < 50) {
#pragma unroll
      for (int i = 0; i < 16; i += 4) {
        float4 v = *(const float4*)(&mem[r * 256 + seg * 64 + i * 4]);
        s += v.x * v.x + v.y * v.y + v.z * v.z + v.w * v.w;
      }
    }
    s += __shfl_xor(s, 1, 64);
    s += __shfl_xor(s, 2, 64);
    if (seg == 0) msq[r] = (r < 50) ? s : 1e30f;
  }
}

// ---------------- fused main kernel: 32 tokens/block, LDS 25600 B ----------------
// __launch_bounds__(256,4): VGPR cap 128 (kernel needs ~84-100; (256,5)'s 48-VGPR
// cap caused 22.8 MB of scratch spill traffic in R3 — never cap below need).
// LDS map (XOR-swizzled 16B chunks: slot = chunk ^ (row & 7)):
//   [0,     16384)  Xs   [32 tok][256] bf16   (X data; later: normalized feats)
//   [16384, 24576)  Hs   [32 tok][128] bf16   (Phase 1 only)
//   [16384, 24704)  distS[32][65] fp32        (Phase 3-4; Hs dead)
//   [16384, 17408)  psum/psumsq [4][32] fp32  (Phase 2a only; before distS)
//   [24704, 25600)  fsqp[4][32] + muS/rstdS/fsqS [32]
__global__ __launch_bounds__(256, 4) void fused_main(
    const float* __restrict__ X, const float* __restrict__ b1v,
    const float* __restrict__ b2v, const float* __restrict__ gammav,
    const float* __restrict__ betav, const ushort_t* __restrict__ W1T,
    const ushort_t* __restrict__ W2T, const ushort_t* __restrict__ memB,
    const float* __restrict__ msq, float* __restrict__ out) {
  __shared__ __align__(16) char smem[25600];
  char* Xs = smem;
  char* Hs = smem + 16384;
  float* distS  = (float*)(smem + 16384);
  float* psum   = (float*)(smem + 16384);
  float* psumsq = (float*)(smem + 16896);
  float* fsqp   = (float*)(smem + 24704);
  float* muS    = (float*)(smem + 25216);
  float* rstdS  = (float*)(smem + 25344);
  float* fsqS   = (float*)(smem + 25472);

  const int tid = threadIdx.x;
  const int wid = tid >> 6;
  const int lane = tid & 63;
  const int l16 = lane & 15;
  const int quad = lane >> 4;

  // ---- Phase 0: stage X tile [32][256] fp32 -> LDS bf16 (swizzled) ----
  const float4* X4 = (const float4*)(X + (size_t)blockIdx.x * 32 * 256);
#pragma unroll
  for (int j = 0; j < 8; ++j) {
    int idx = j * 256 + tid;
    float4 v = X4[idx];
    int row = idx >> 6;
    int c = (idx & 63) >> 1;
    int half = idx & 1;
    int slot = c ^ (row & 7);
    unsigned int p0 = f2b(v.x) | ((unsigned int)f2b(v.y) << 16);
    unsigned int p1 = f2b(v.z) | ((unsigned int)f2b(v.w) << 16);
    *(uint2*)(Xs + row * 512 + slot * 16 + half * 8) = make_uint2(p0, p1);
  }

  // F^T accumulators: (fcol = wid*64 + mt*16 + quad*4 + reg, token = nt*16 + l16)
  f32x4 acc2[4][2];
#pragma unroll
  for (int mt = 0; mt < 4; ++mt) {
    const float4 bb = *(const float4*)(&b2v[wid * 64 + mt * 16 + quad * 4]);
#pragma unroll
    for (int nt = 0; nt < 2; ++nt) {
      acc2[mt][nt][0] = bb.x; acc2[mt][nt][1] = bb.y;
      acc2[mt][nt][2] = bb.z; acc2[mt][nt][3] = bb.w;
    }
  }

  __syncthreads();

  // ---- Phase 1: chunked GEMM1 -> relu -> Hs; GEMM2 accumulate ----
  for (int cc = 0; cc < 4; ++cc) {
    int hbase = cc * 128 + wid * 32;
    f32x4 acc1[2][2];
#pragma unroll
    for (int mt = 0; mt < 2; ++mt) {
      const float4 bb = *(const float4*)(&b1v[hbase + mt * 16 + quad * 4]);
#pragma unroll
      for (int nt = 0; nt < 2; ++nt) {
        acc1[mt][nt][0] = bb.x; acc1[mt][nt][1] = bb.y;
        acc1[mt][nt][2] = bb.z; acc1[mt][nt][3] = bb.w;
      }
    }
#pragma unroll
    for (int kk = 0; kk < 8; ++kk) {
      int k0 = kk * 32 + quad * 8;
      bf16x8 a[2], b[2];
#pragma unroll
      for (int mt = 0; mt < 2; ++mt)
        a[mt] = *(const bf16x8*)(W1T + (hbase + mt * 16 + l16) * 256 + k0);
      int c = kk * 4 + quad;
#pragma unroll
      for (int nt = 0; nt < 2; ++nt) {
        int t = nt * 16 + l16;
        b[nt] = *(const bf16x8*)(Xs + t * 512 + (c ^ (t & 7)) * 16);
      }
#pragma unroll
      for (int mt = 0; mt < 2; ++mt)
#pragma unroll
        for (int nt = 0; nt < 2; ++nt)
          acc1[mt][nt] = __builtin_amdgcn_mfma_f32_16x16x32_bf16(
              a[mt], b[nt], acc1[mt][nt], 0, 0, 0);
    }
    __syncthreads();  // previous GEMM2 done reading Hs
#pragma unroll
    for (int mt = 0; mt < 2; ++mt) {
#pragma unroll
      for (int nt = 0; nt < 2; ++nt) {
        int token = nt * 16 + l16;
        int c = wid * 4 + mt * 2 + (quad >> 1);
        int half = quad & 1;
        int slot = c ^ (token & 7);
        f32x4 v = acc1[mt][nt];
        unsigned int p0 = f2b(fmaxf(v[0], 0.f)) | ((unsigned int)f2b(fmaxf(v[1], 0.f)) << 16);
        unsigned int p1 = f2b(fmaxf(v[2], 0.f)) | ((unsigned int)f2b(fmaxf(v[3], 0.f)) << 16);
        *(uint2*)(Hs + token * 256 + slot * 16 + half * 8) = make_uint2(p0, p1);
      }
    }
    __syncthreads();
#pragma unroll
    for (int k2 = 0; k2 < 4; ++k2) {
      int c = k2 * 4 + quad;
      bf16x8 a[4], b[2];
#pragma unroll
      for (int mt = 0; mt < 4; ++mt)
        a[mt] = *(const bf16x8*)(W2T + (wid * 64 + mt * 16 + l16) * 512 +
                                 cc * 128 + k2 * 32 + quad * 8);
#pragma unroll
      for (int nt = 0; nt < 2; ++nt) {
        int t = nt * 16 + l16;
        b[nt] = *(const bf16x8*)(Hs + t * 256 + (c ^ (t & 7)) * 16);
      }
#pragma unroll
      for (int mt = 0; mt < 4; ++mt)
#pragma unroll
        for (int nt = 0; nt < 2; ++nt)
          acc2[mt][nt] = __builtin_amdgcn_mfma_f32_16x16x32_bf16(
              a[mt], b[nt], acc2[mt][nt], 0, 0, 0);
    }
  }
  __syncthreads();  // Hs dead; psum overlay becomes safe

  // ---- Phase 2a: per-token sum/sumsq for LayerNorm ----
#pragma unroll
  for (int nt = 0; nt < 2; ++nt) {
    float s = 0.f, sq = 0.f;
#pragma unroll
    for (int mt = 0; mt < 4; ++mt)
#pragma unroll
      for (int r = 0; r < 4; ++r) {
        float v = acc2[mt][nt][r];
        s += v; sq += v * v;
      }
    s += __shfl_xor(s, 16, 64); sq += __shfl_xor(sq, 16, 64);
    s += __shfl_xor(s, 32, 64); sq += __shfl_xor(sq, 32, 64);
    if (quad == 0) {
      psum[wid * 32 + nt * 16 + l16] = s;
      psumsq[wid * 32 + nt * 16 + l16] = sq;
    }
  }
  __syncthreads();
  if (tid < 32) {
    float s = psum[tid] + psum[32 + tid] + psum[64 + tid] + psum[96 + tid];
    float sq = psumsq[tid] + psumsq[32 + tid] + psumsq[64 + tid] + psumsq[96 + tid];
    float mu = s * (1.f / 256.f);
    float var = sq * (1.f / 256.f) - mu * mu;
    muS[tid] = mu;
    rstdS[tid] = rsqrtf(var + 1e-5f);
  }
  __syncthreads();

  // ---- Phase 2b: normalize, write feats bf16 (token-major, swizzled), fsq ----
  {
    float4 g[4], be[4];
#pragma unroll
    for (int mt = 0; mt < 4; ++mt) {
      g[mt]  = *(const float4*)(&gammav[wid * 64 + mt * 16 + quad * 4]);
      be[mt] = *(const float4*)(&betav[wid * 64 + mt * 16 + quad * 4]);
    }
#pragma unroll
    for (int nt = 0; nt < 2; ++nt) {
      int token = nt * 16 + l16;
      float mu = muS[token], rs = rstdS[token];
      float fs = 0.f;
#pragma unroll
      for (int mt = 0; mt < 4; ++mt) {
        float y0 = (acc2[mt][nt][0] - mu) * rs * g[mt].x + be[mt].x;
        float y1 = (acc2[mt][nt][1] - mu) * rs * g[mt].y + be[mt].y;
        float y2 = (acc2[mt][nt][2] - mu) * rs * g[mt].z + be[mt].z;
        float y3 = (acc2[mt][nt][3] - mu) * rs * g[mt].w + be[mt].w;
        fs += y0 * y0 + y1 * y1 + y2 * y2 + y3 * y3;
        int c = wid * 8 + mt * 2 + (quad >> 1);
        int half = quad & 1;
        int slot = c ^ (token & 7);
        unsigned int p0 = f2b(y0) | ((unsigned int)f2b(y1) << 16);
        unsigned int p1 = f2b(y2) | ((unsigned int)f2b(y3) << 16);
        *(uint2*)(Xs + token * 512 + slot * 16 + half * 8) = make_uint2(p0, p1);
      }
      fs += __shfl_xor(fs, 16, 64);
      fs += __shfl_xor(fs, 32, 64);
      if (quad == 0) fsqp[wid * 32 + token] = fs;
    }
  }
  __syncthreads();

  if (tid < 32)
    fsqS[tid] = fsqp[tid] + fsqp[32 + tid] + fsqp[64 + tid] + fsqp[96 + tid];

  // ---- Phase 3: dots GEMM. token-half = wid&1, memcol-half = wid>>1 ----
  const int th = wid & 1;
  const int mh = wid >> 1;
  f32x4 acc3[2];
#pragma unroll
  for (int nt = 0; nt < 2; ++nt) {
    acc3[nt][0] = 0.f; acc3[nt][1] = 0.f; acc3[nt][2] = 0.f; acc3[nt][3] = 0.f;
  }
#pragma unroll
  for (int kk = 0; kk < 8; ++kk) {
    int c = kk * 4 + quad;
    int t = th * 16 + l16;
    bf16x8 a = *(const bf16x8*)(Xs + t * 512 + (c ^ (t & 7)) * 16);
#pragma unroll
    for (int nt = 0; nt < 2; ++nt) {
      int mrow = mh * 32 + nt * 16 + l16;
      bf16x8 b = *(const bf16x8*)(memB + mrow * 256 + kk * 32 + quad * 8);
      acc3[nt] = __builtin_amdgcn_mfma_f32_16x16x32_bf16(a, b, acc3[nt], 0, 0, 0);
    }
  }
  __syncthreads();  // fsqS visible; all waves done reading Xs; distS overlay safe
  {
    float4 fsq4 = *(const float4*)(&fsqS[th * 16 + quad * 4]);
#pragma unroll
    for (int nt = 0; nt < 2; ++nt) {
      int col = mh * 32 + nt * 16 + l16;
      float mq = msq[col];
#pragma unroll
      for (int r = 0; r < 4; ++r) {
        float fv = (r == 0) ? fsq4.x : (r == 1) ? fsq4.y : (r == 2) ? fsq4.z : fsq4.w;
        float d2 = fv + mq - 2.f * acc3[nt][r];
        float d = sqrtf(fmaxf(d2, 0.f));
        int row = th * 16 + quad * 4 + r;
        distS[row * 65 + col] = d;
      }
    }
  }
  __syncthreads();

  // ---- Phase 4: top-5 smallest of 50, mean, sigmoid ----
  if (tid < 32) {
    float b0 = 1e30f, b1 = 1e30f, b2 = 1e30f, b3 = 1e30f, b4 = 1e30f;
    const float* dr = &distS[tid * 65];
    for (int j = 0; j < 50; ++j) {
      float v = dr[j];
      b4 = fminf(b4, v);
      float t;
      if (b4 < b3) { t = b3; b3 = b4; b4 = t; }
      if (b3 < b2) { t = b2; b2 = b3; b3 = t; }
      if (b2 < b1) { t = b1; b1 = b2; b2 = t; }
      if (b1 < b0) { t = b0; b0 = b1; b1 = t; }
    }
    float avg = (b0 + b1 + b2 + b3 + b4) * 0.2f;
    out[blockIdx.x * 32 + tid] = 1.f / (1.f + __expf(-(avg - 1.f)));
  }
}

// ---------------- launch ----------------
extern "C" void kernel_launch(void* const* d_in, const int* in_sizes, int n_in,
                              void* d_out, int out_size, void* d_ws, size_t ws_size,
                              hipStream_t stream) {
  const float* X   = (const float*)d_in[0];
  const float* mem = (const float*)d_in[1];
  const float* W1  = (const float*)d_in[2];
  const float* b1  = (const float*)d_in[3];
  const float* W2  = (const float*)d_in[4];
  const float* b2  = (const float*)d_in[5];
  const float* g   = (const float*)d_in[6];
  const float* be  = (const float*)d_in[7];
  float* out = (float*)d_out;

  ushort_t* W1T  = (ushort_t*)d_ws;
  ushort_t* W2T  = W1T + 131072;
  ushort_t* memB = W2T + 131072;
  float* msq = (float*)(memB + 16384);

  prep<<<65, 256, 0, stream>>>(W1, W2, mem, W1T, W2T, memB, msq);
  fused_main<<<2048, 256, 0, stream>>>(X, b1, b2, g, be, W1T, W2T, memB, msq, out);
}

// Round 5
// 201.138 us; speedup vs baseline: 1.3741x; 1.2378x over previous
//
#include <hip/hip_runtime.h>
#include <math.h>

typedef __attribute__((ext_vector_type(8))) short bf16x8;
typedef __attribute__((ext_vector_type(4))) float f32x4;
typedef unsigned short ushort_t;

static __device__ __forceinline__ unsigned short f2b(float x) {
  unsigned int u = __float_as_uint(x);
  u += 0x7FFFu + ((u >> 16) & 1u);  // round-to-nearest-even
  return (unsigned short)(u >> 16);
}

// ---------------- prep kernel (unchanged) ----------------
static __device__ __forceinline__ void transpose_tile(
    const float* __restrict__ src, ushort_t* __restrict__ dst, int srcC,
    int dstC, int r0, int c0, ushort_t (*T)[72], int t) {
#pragma unroll
  for (int j = 0; j < 4; ++j) {
    int idx = j * 256 + t;
    int lr = idx >> 4;
    int lc = (idx & 15) << 2;
    float4 v = *(const float4*)(&src[(size_t)(r0 + lr) * srcC + c0 + lc]);
    T[lr][lc + 0] = f2b(v.x);
    T[lr][lc + 1] = f2b(v.y);
    T[lr][lc + 2] = f2b(v.z);
    T[lr][lc + 3] = f2b(v.w);
  }
  __syncthreads();
#pragma unroll
  for (int j = 0; j < 2; ++j) {
    int oidx = j * 256 + t;
    int lc = oidx >> 3;
    int rch = (oidx & 7) << 3;
    ushort_t tmp[8];
#pragma unroll
    for (int k = 0; k < 8; ++k) tmp[k] = T[rch + k][lc];
    *(uint4*)(&dst[(size_t)(c0 + lc) * dstC + r0 + rch]) = *(uint4*)tmp;
  }
}

__global__ void prep(const float* __restrict__ W1, const float* __restrict__ W2,
                     const float* __restrict__ mem, ushort_t* __restrict__ W1T,
                     ushort_t* __restrict__ W2T, ushort_t* __restrict__ memB,
                     float* __restrict__ msq) {
  __shared__ ushort_t T[64][72];
  int b = blockIdx.x;
  int t = threadIdx.x;
  if (b < 32) {
    int tr = b >> 3, tc = b & 7;
    transpose_tile(W1, W1T, 512, 256, tr * 64, tc * 64, T, t);
  } else if (b < 64) {
    int bb = b - 32;
    int tr = bb >> 2, tc = bb & 3;
    transpose_tile(W2, W2T, 256, 512, tr * 64, tc * 64, T, t);
  } else {
    for (int i = t; i < 16384; i += 256) {
      int r = i >> 8;
      memB[i] = (r < 50) ? f2b(mem[i]) : (ushort_t)0;
    }
    int r = t >> 2, seg = t & 3;
    float s = 0.f;
    if (r < 50) {
#pragma unroll
      for (int i = 0; i < 16; i += 4) {
        float4 v = *(const float4*)(&mem[r * 256 + seg * 64 + i * 4]);
        s += v.x * v.x + v.y * v.y + v.z * v.z + v.w * v.w;
      }
    }
    s += __shfl_xor(s, 1, 64);
    s += __shfl_xor(s, 2, 64);
    if (seg == 0) msq[r] = (r < 50) ? s : 1e30f;
  }
}

// ---------------- fused main: 64 tokens/block, explicit weight prefetch ------
// __launch_bounds__(256,2): 256-VGPR budget so all 16 W1T frags + 16 W2T frags
// can be register-resident (R4 lesson: compiler register-minimizes to ~56 VGPR
// and serializes load->MFMA chains; we hoist loads a phase ahead instead).
// LDS 50176 B, swizzled 16B chunks: slot = chunk ^ (row & 7).
//   [0,     32768)  Xs   [64 tok][256] bf16 (rows 512 B; later normalized feats)
//   [32768, 49152)  Hs   [64 tok][128] bf16 (rows 256 B; Phase 1 only)
//   [32768, 49408)  distS[64][65] fp32     (Phase 3-4; Hs dead)
//   [32768, 35840)  psum/psumsq/fsqp [4][64] fp32 (Phase 2 only; before distS)
//   [49408, 50176)  muS/rstdS/fsqS [64] fp32
__global__ __launch_bounds__(256, 2) void fused_main(
    const float* __restrict__ X, const float* __restrict__ b1v,
    const float* __restrict__ b2v, const float* __restrict__ gammav,
    const float* __restrict__ betav, const ushort_t* __restrict__ W1T,
    const ushort_t* __restrict__ W2T, const ushort_t* __restrict__ memB,
    const float* __restrict__ msq, float* __restrict__ out) {
  __shared__ __align__(16) char smem[50176];
  char* Xs = smem;
  char* Hs = smem + 32768;
  float* distS  = (float*)(smem + 32768);
  float* psum   = (float*)(smem + 32768);   // [4][64]
  float* psumsq = (float*)(smem + 33792);   // [4][64]
  float* fsqp   = (float*)(smem + 34816);   // [4][64]
  float* muS    = (float*)(smem + 49408);
  float* rstdS  = (float*)(smem + 49664);
  float* fsqS   = (float*)(smem + 49920);

  const int tid = threadIdx.x;
  const int wid = tid >> 6;
  const int lane = tid & 63;
  const int l16 = lane & 15;
  const int quad = lane >> 4;

  // ---- Prefetch W1T frags for cc=0 (complete during Phase 0 / barrier) ----
  bf16x8 w1f[2][8];
  {
    int hbase = wid * 32;
#pragma unroll
    for (int mt = 0; mt < 2; ++mt)
#pragma unroll
      for (int kk = 0; kk < 8; ++kk)
        w1f[mt][kk] = *(const bf16x8*)(W1T + (hbase + mt * 16 + l16) * 256 +
                                       kk * 32 + quad * 8);
  }

  // ---- Phase 0: stage X tile [64][256] fp32 -> LDS bf16 (swizzled) ----
  const float4* X4 = (const float4*)(X + (size_t)blockIdx.x * 64 * 256);
#pragma unroll
  for (int j = 0; j < 16; ++j) {
    int idx = j * 256 + tid;             // 4096 float4 = [64 rows][64 f4]
    float4 v = X4[idx];
    int row = idx >> 6;
    int f = idx & 63;
    int slot = (f >> 1) ^ (row & 7);
    unsigned int p0 = f2b(v.x) | ((unsigned int)f2b(v.y) << 16);
    unsigned int p1 = f2b(v.z) | ((unsigned int)f2b(v.w) << 16);
    *(uint2*)(Xs + row * 512 + slot * 16 + (f & 1) * 8) = make_uint2(p0, p1);
  }

  // F^T accumulators: (fcol = wid*64 + mt*16 + quad*4 + reg, token = nt*16+l16)
  f32x4 acc2[4][4];
#pragma unroll
  for (int mt = 0; mt < 4; ++mt) {
    const float4 bb = *(const float4*)(&b2v[wid * 64 + mt * 16 + quad * 4]);
#pragma unroll
    for (int nt = 0; nt < 4; ++nt) {
      acc2[mt][nt][0] = bb.x; acc2[mt][nt][1] = bb.y;
      acc2[mt][nt][2] = bb.z; acc2[mt][nt][3] = bb.w;
    }
  }

  __syncthreads();

  // ---- Phase 1: per cc: GEMM1 (reg-resident W1) -> Hs; GEMM2 accumulate ----
  for (int cc = 0; cc < 4; ++cc) {
    int hbase = cc * 128 + wid * 32;
    f32x4 acc1[2][4];
#pragma unroll
    for (int mt = 0; mt < 2; ++mt) {
      const float4 bb = *(const float4*)(&b1v[hbase + mt * 16 + quad * 4]);
#pragma unroll
      for (int nt = 0; nt < 4; ++nt) {
        acc1[mt][nt][0] = bb.x; acc1[mt][nt][1] = bb.y;
        acc1[mt][nt][2] = bb.z; acc1[mt][nt][3] = bb.w;
      }
    }
    // GEMM1 from registers + Xs
#pragma unroll
    for (int kk = 0; kk < 8; ++kk) {
      int c = kk * 4 + quad;
      bf16x8 b[4];
#pragma unroll
      for (int nt = 0; nt < 4; ++nt) {
        int t = nt * 16 + l16;
        b[nt] = *(const bf16x8*)(Xs + t * 512 + ((c ^ (t & 7)) << 4));
      }
#pragma unroll
      for (int mt = 0; mt < 2; ++mt)
#pragma unroll
        for (int nt = 0; nt < 4; ++nt)
          acc1[mt][nt] = __builtin_amdgcn_mfma_f32_16x16x32_bf16(
              w1f[mt][kk], b[nt], acc1[mt][nt], 0, 0, 0);
    }
    // Issue W2T(cc) loads now: barrier drain below absorbs their latency.
    bf16x8 w2f[4][4];
#pragma unroll
    for (int mt = 0; mt < 4; ++mt)
#pragma unroll
      for (int k2 = 0; k2 < 4; ++k2)
        w2f[mt][k2] = *(const bf16x8*)(W2T + (wid * 64 + mt * 16 + l16) * 512 +
                                       cc * 128 + k2 * 32 + quad * 8);
    __syncthreads();  // previous GEMM2 done reading Hs
#pragma unroll
    for (int mt = 0; mt < 2; ++mt) {
#pragma unroll
      for (int nt = 0; nt < 4; ++nt) {
        int token = nt * 16 + l16;
        int c = wid * 4 + mt * 2 + (quad >> 1);
        int slot = c ^ (token & 7);
        f32x4 v = acc1[mt][nt];
        unsigned int p0 = f2b(fmaxf(v[0], 0.f)) | ((unsigned int)f2b(fmaxf(v[1], 0.f)) << 16);
        unsigned int p1 = f2b(fmaxf(v[2], 0.f)) | ((unsigned int)f2b(fmaxf(v[3], 0.f)) << 16);
        *(uint2*)(Hs + token * 256 + slot * 16 + (quad & 1) * 8) = make_uint2(p0, p1);
      }
    }
    __syncthreads();
    // Prefetch next cc's W1T frags; they complete during GEMM2's MFMAs.
    if (cc < 3) {
      int hb = (cc + 1) * 128 + wid * 32;
#pragma unroll
      for (int mt = 0; mt < 2; ++mt)
#pragma unroll
        for (int kk = 0; kk < 8; ++kk)
          w1f[mt][kk] = *(const bf16x8*)(W1T + (hb + mt * 16 + l16) * 256 +
                                         kk * 32 + quad * 8);
    }
    // GEMM2 from registers + Hs
#pragma unroll
    for (int k2 = 0; k2 < 4; ++k2) {
      int c = k2 * 4 + quad;
      bf16x8 b[4];
#pragma unroll
      for (int nt = 0; nt < 4; ++nt) {
        int t = nt * 16 + l16;
        b[nt] = *(const bf16x8*)(Hs + t * 256 + ((c ^ (t & 7)) << 4));
      }
#pragma unroll
      for (int mt = 0; mt < 4; ++mt)
#pragma unroll
        for (int nt = 0; nt < 4; ++nt)
          acc2[mt][nt] = __builtin_amdgcn_mfma_f32_16x16x32_bf16(
              w2f[mt][k2], b[nt], acc2[mt][nt], 0, 0, 0);
    }
  }
  __syncthreads();  // Hs dead; psum overlay safe

  // ---- Phase 2a: per-token sum/sumsq for LayerNorm ----
#pragma unroll
  for (int nt = 0; nt < 4; ++nt) {
    float s = 0.f, sq = 0.f;
#pragma unroll
    for (int mt = 0; mt < 4; ++mt)
#pragma unroll
      for (int r = 0; r < 4; ++r) {
        float v = acc2[mt][nt][r];
        s += v; sq += v * v;
      }
    s += __shfl_xor(s, 16, 64); sq += __shfl_xor(sq, 16, 64);
    s += __shfl_xor(s, 32, 64); sq += __shfl_xor(sq, 32, 64);
    if (quad == 0) {
      psum[wid * 64 + nt * 16 + l16] = s;
      psumsq[wid * 64 + nt * 16 + l16] = sq;
    }
  }
  __syncthreads();
  if (tid < 64) {
    float s = psum[tid] + psum[64 + tid] + psum[128 + tid] + psum[192 + tid];
    float sq = psumsq[tid] + psumsq[64 + tid] + psumsq[128 + tid] + psumsq[192 + tid];
    float mu = s * (1.f / 256.f);
    float var = sq * (1.f / 256.f) - mu * mu;
    muS[tid] = mu;
    rstdS[tid] = rsqrtf(var + 1e-5f);
  }
  __syncthreads();

  // ---- Phase 2b: normalize, write feats bf16 (token-major, swizzled), fsq ----
  {
    float4 g[4], be[4];
#pragma unroll
    for (int mt = 0; mt < 4; ++mt) {
      g[mt]  = *(const float4*)(&gammav[wid * 64 + mt * 16 + quad * 4]);
      be[mt] = *(const float4*)(&betav[wid * 64 + mt * 16 + quad * 4]);
    }
#pragma unroll
    for (int nt = 0; nt < 4; ++nt) {
      int token = nt * 16 + l16;
      float mu = muS[token], rs = rstdS[token];
      float fs = 0.f;
#pragma unroll
      for (int mt = 0; mt < 4; ++mt) {
        float y0 = (acc2[mt][nt][0] - mu) * rs * g[mt].x + be[mt].x;
        float y1 = (acc2[mt][nt][1] - mu) * rs * g[mt].y + be[mt].y;
        float y2 = (acc2[mt][nt][2] - mu) * rs * g[mt].z + be[mt].z;
        float y3 = (acc2[mt][nt][3] - mu) * rs * g[mt].w + be[mt].w;
        fs += y0 * y0 + y1 * y1 + y2 * y2 + y3 * y3;
        int c = wid * 8 + mt * 2 + (quad >> 1);
        int slot = c ^ (token & 7);
        unsigned int p0 = f2b(y0) | ((unsigned int)f2b(y1) << 16);
        unsigned int p1 = f2b(y2) | ((unsigned int)f2b(y3) << 16);
        *(uint2*)(Xs + token * 512 + slot * 16 + (quad & 1) * 8) = make_uint2(p0, p1);
      }
      fs += __shfl_xor(fs, 16, 64);
      fs += __shfl_xor(fs, 32, 64);
      if (quad == 0) fsqp[wid * 64 + token] = fs;
    }
  }
  __syncthreads();

  if (tid < 64)
    fsqS[tid] = fsqp[tid] + fsqp[64 + tid] + fsqp[128 + tid] + fsqp[192 + tid];

  // ---- Phase 3: dots GEMM: wave's 16 tokens vs 64 padded memory rows ----
  // Hoist all memB frags (L1/L2-hot: every block reads the same 32 KB).
  bf16x8 mf[4][8];
#pragma unroll
  for (int nt = 0; nt < 4; ++nt)
#pragma unroll
    for (int kk = 0; kk < 8; ++kk)
      mf[nt][kk] = *(const bf16x8*)(memB + (nt * 16 + l16) * 256 + kk * 32 + quad * 8);
  f32x4 acc3[4];
#pragma unroll
  for (int nt = 0; nt < 4; ++nt) {
    acc3[nt][0] = 0.f; acc3[nt][1] = 0.f; acc3[nt][2] = 0.f; acc3[nt][3] = 0.f;
  }
  const int t3 = wid * 16 + l16;
#pragma unroll
  for (int kk = 0; kk < 8; ++kk) {
    int c = kk * 4 + quad;
    bf16x8 a = *(const bf16x8*)(Xs + t3 * 512 + ((c ^ (t3 & 7)) << 4));
#pragma unroll
    for (int nt = 0; nt < 4; ++nt)
      acc3[nt] = __builtin_amdgcn_mfma_f32_16x16x32_bf16(a, mf[nt][kk], acc3[nt], 0, 0, 0);
  }
  __syncthreads();  // fsqS visible; all waves done reading Xs/fsqp; distS safe
  {
    float4 fsq4 = *(const float4*)(&fsqS[wid * 16 + quad * 4]);
#pragma unroll
    for (int nt = 0; nt < 4; ++nt) {
      int col = nt * 16 + l16;
      float mq = msq[col];
#pragma unroll
      for (int r = 0; r < 4; ++r) {
        float fv = (r == 0) ? fsq4.x : (r == 1) ? fsq4.y : (r == 2) ? fsq4.z : fsq4.w;
        float d2 = fv + mq - 2.f * acc3[nt][r];
        float d = sqrtf(fmaxf(d2, 0.f));
        int row = wid * 16 + quad * 4 + r;
        distS[row * 65 + col] = d;
      }
    }
  }
  __syncthreads();

  // ---- Phase 4: top-5 smallest of 50, mean, sigmoid ----
  if (tid < 64) {
    float b0 = 1e30f, b1 = 1e30f, b2 = 1e30f, b3 = 1e30f, b4 = 1e30f;
    const float* dr = &distS[tid * 65];
    for (int j = 0; j < 50; ++j) {
      float v = dr[j];
      b4 = fminf(b4, v);
      float t;
      if (b4 < b3) { t = b3; b3 = b4; b4 = t; }
      if (b3 < b2) { t = b2; b2 = b3; b3 = t; }
      if (b2 < b1) { t = b1; b1 = b2; b2 = t; }
      if (b1 < b0) { t = b0; b0 = b1; b1 = t; }
    }
    float avg = (b0 + b1 + b2 + b3 + b4) * 0.2f;
    out[blockIdx.x * 64 + tid] = 1.f / (1.f + __expf(-(avg - 1.f)));
  }
}

// ---------------- launch ----------------
extern "C" void kernel_launch(void* const* d_in, const int* in_sizes, int n_in,
                              void* d_out, int out_size, void* d_ws, size_t ws_size,
                              hipStream_t stream) {
  const float* X   = (const float*)d_in[0];
  const float* mem = (const float*)d_in[1];
  const float* W1  = (const float*)d_in[2];
  const float* b1  = (const float*)d_in[3];
  const float* W2  = (const float*)d_in[4];
  const float* b2  = (const float*)d_in[5];
  const float* g   = (const float*)d_in[6];
  const float* be  = (const float*)d_in[7];
  float* out = (float*)d_out;

  ushort_t* W1T  = (ushort_t*)d_ws;
  ushort_t* W2T  = W1T + 131072;
  ushort_t* memB = W2T + 131072;
  float* msq = (float*)(memB + 16384);

  prep<<<65, 256, 0, stream>>>(W1, W2, mem, W1T, W2T, memB, msq);
  fused_main<<<1024, 256, 0, stream>>>(X, b1, b2, g, be, W1T, W2T, memB, msq, out);
}